// Round 8
// baseline (131.492 us; speedup 1.0000x reference)
//
#include <hip/hip_runtime.h>

// toy_gnn scatter-add: out[dst[e], f] += w_mp * edge_weight[e] * x[src[e], f]
// N=100000, E=1600000, F=32, fp32.
//
// Round 8: occupancy + MLP tuning of the R7 pipeline.
//   - bin_edges: 391 blocks (CHUNK 4096) -- R7's 196 blocks left 60 CUs idle
//     (LDS-atomic chains unhidden). Runs stay ~10.5 records = 84 B, dense.
//   - sort_gather: SUBS=2 (782 blocks, 128 nodes each). No ballot-compact /
//     'mine' buffer: two passes over the L2-hot bucket records (pass1 = hist
//     on match, shuffle scan, pass2 = place into LDS 'sorted'). Gather is
//     4 thr/node x 8 floats with 4-record unroll -> 8 x-loads in flight per
//     thread (2x R7's MLP). Zero fp32 atomics anywhere (R6 lesson: LDS fp32
//     atomics via generic ptr = flat-atomic disaster; registers only).
//   - init_cursors kernel replaced by 1.5 KB hipMemsetAsync (zero-based
//     cursors, positions biased by b*CAP_C).

constexpr int N_NODES = 100000;
constexpr int N_EDGES = 1600000;
constexpr int F_DIM   = 32;

// ---- binning (coarse) ----
constexpr int NPB_C = 256;                           // nodes per coarse bucket
constexpr int NB_C  = (N_NODES + NPB_C - 1) / NPB_C; // 391
constexpr int CAP_C = 4608;                          // mean 4096 + 8 sigma(64)

constexpr int BIN_THREADS = 512;
constexpr int BIN_EPT     = 8;
constexpr int BIN_CHUNK   = BIN_THREADS * BIN_EPT;                  // 4096
constexpr int BIN_BLOCKS  = (N_EDGES + BIN_CHUNK - 1) / BIN_CHUNK;  // 391

// ---- fused sort+gather ----
constexpr int SUBS  = 2;                             // blocks per coarse bucket
constexpr int NPB_F = NPB_C / SUBS;                  // 128 nodes per block
constexpr int MCAP  = 2560;                          // mean 2048 + >10 sigma(45)
constexpr int SG_THREADS = 512;

// ---------------- workspace layout (bytes) ----------------
constexpr size_t WS_CURSOR  = 0;                     // NB_C ints (memset to 0)
constexpr size_t WS_RECORDS = 4096;                  // NB_C*CAP_C uint2
constexpr size_t WS_NEEDED  = WS_RECORDS + (size_t)NB_C * CAP_C * 8;  // ~14.4 MB

__global__ __launch_bounds__(BIN_THREADS) void bin_edges(
    const int* __restrict__ src, const int* __restrict__ dst,
    const float* __restrict__ ew, const float* __restrict__ w_mp,
    int* __restrict__ gcursor, uint2* __restrict__ records)
{
    __shared__ int lhist[NB_C];
    __shared__ int lbase[NB_C];
    if (threadIdx.x < NB_C) lhist[threadIdx.x] = 0;
    __syncthreads();

    const float w = w_mp[0];
    const int base_e = blockIdx.x * BIN_CHUNK;
    int   bkt[BIN_EPT];
    uint2 rec[BIN_EPT];

    #pragma unroll
    for (int i = 0; i < BIN_EPT; ++i) {
        int e = base_e + threadIdx.x + i * BIN_THREADS;
        bkt[i] = -1;
        if (e < N_EDGES) {
            int d = dst[e];
            int b = d >> 8;                     // coarse bucket (256 nodes)
            bkt[i] = b;
            rec[i].x = __float_as_uint(w * ew[e]);
            rec[i].y = (unsigned)src[e] | ((unsigned)(d & 255) << 24);
            atomicAdd(&lhist[b], 1);
        }
    }
    __syncthreads();

    if (threadIdx.x < NB_C) {
        int c = lhist[threadIdx.x];
        // gcursor zero-based (memset); returns this block's base count
        lbase[threadIdx.x] = c ? atomicAdd(&gcursor[threadIdx.x], c) : 0;
        lhist[threadIdx.x] = 0;
    }
    __syncthreads();

    #pragma unroll
    for (int i = 0; i < BIN_EPT; ++i) {
        int b = bkt[i];
        if (b >= 0) {
            int ofs = lbase[b] + atomicAdd(&lhist[b], 1);
            if (ofs < CAP_C)                    // overflow guard (8-sigma margin)
                records[b * CAP_C + ofs] = rec[i];
        }
    }
}

__global__ __launch_bounds__(SG_THREADS) void sort_gather(
    const int*   __restrict__ gcursor,
    const uint2* __restrict__ records,
    const float* __restrict__ x,
    float*       __restrict__ out)
{
    __shared__ uint2 sorted[MCAP];       // 20.5 KB node-sorted records
    __shared__ int   hist[NPB_F];
    __shared__ int   offs[NPB_F + 1];
    __shared__ int   cursor[NPB_F];

    const int coarse   = blockIdx.x >> 1;
    const unsigned sub = blockIdx.x & 1;
    const int t        = threadIdx.x;

    if (t < NPB_F) hist[t] = 0;
    __syncthreads();

    const int rbase = coarse * CAP_C;
    const int cnt   = min(gcursor[coarse], CAP_C);

    // pass 1: histogram of this sub's records (records are L2-hot, 36 KB)
    for (int j = t; j < cnt; j += SG_THREADS) {
        unsigned ry = records[rbase + j].y;
        if ((ry >> 31) == sub)                  // dl>>7 == sub
            atomicAdd(&hist[(ry >> 24) & 127], 1);
    }
    __syncthreads();

    // wave 0: scan 128 counters as two shuffle-scanned 64-chunks
    if (t < 64) {
        int v0  = hist[t];
        int inc = v0;
        #pragma unroll
        for (int d = 1; d < 64; d <<= 1) {
            int o = __shfl_up(inc, d, 64);
            if (t >= d) inc += o;
        }
        offs[t + 1] = inc;
        cursor[t]   = inc - v0;
        int tot0 = __shfl(inc, 63, 64);
        int v1   = hist[64 + t];
        int inc1 = v1;
        #pragma unroll
        for (int d = 1; d < 64; d <<= 1) {
            int o = __shfl_up(inc1, d, 64);
            if (t >= d) inc1 += o;
        }
        offs[64 + t + 1] = tot0 + inc1;
        cursor[64 + t]   = tot0 + inc1 - v1;
        if (t == 0) offs[0] = 0;
    }
    __syncthreads();

    // pass 2: place into LDS in node order
    for (int j = t; j < cnt; j += SG_THREADS) {
        uint2 r = records[rbase + j];
        if ((r.y >> 31) == sub) {
            int slot = atomicAdd(&cursor[(r.y >> 24) & 127], 1);
            if (slot < MCAP) sorted[slot] = r;  // >10-sigma margin
        }
    }
    __syncthreads();

    // gather: 4 threads/node, 8 floats each, 4-record unroll (8 loads in flight)
    const int node  = t >> 2;
    const int h     = (t & 3) * 8;
    const int gnode = coarse * NPB_C + (int)sub * NPB_F + node;
    if (gnode >= N_NODES) return;

    int j  = min(offs[node], MCAP);
    int je = min(offs[node + 1], MCAP);
    float4 accA = make_float4(0.f, 0.f, 0.f, 0.f);
    float4 accB = make_float4(0.f, 0.f, 0.f, 0.f);

    for (; j + 4 <= je; j += 4) {
        uint2 r0 = sorted[j + 0];
        uint2 r1 = sorted[j + 1];
        uint2 r2 = sorted[j + 2];
        uint2 r3 = sorted[j + 3];
        const float* p0 = x + (size_t)(r0.y & 0xFFFFFFu) * F_DIM + h;
        const float* p1 = x + (size_t)(r1.y & 0xFFFFFFu) * F_DIM + h;
        const float* p2 = x + (size_t)(r2.y & 0xFFFFFFu) * F_DIM + h;
        const float* p3 = x + (size_t)(r3.y & 0xFFFFFFu) * F_DIM + h;
        float4 a0 = *reinterpret_cast<const float4*>(p0);
        float4 b0 = *reinterpret_cast<const float4*>(p0 + 4);
        float4 a1 = *reinterpret_cast<const float4*>(p1);
        float4 b1 = *reinterpret_cast<const float4*>(p1 + 4);
        float4 a2 = *reinterpret_cast<const float4*>(p2);
        float4 b2 = *reinterpret_cast<const float4*>(p2 + 4);
        float4 a3 = *reinterpret_cast<const float4*>(p3);
        float4 b3 = *reinterpret_cast<const float4*>(p3 + 4);
        float c0 = __uint_as_float(r0.x), c1 = __uint_as_float(r1.x);
        float c2 = __uint_as_float(r2.x), c3 = __uint_as_float(r3.x);
        accA.x += c0 * a0.x + c1 * a1.x + c2 * a2.x + c3 * a3.x;
        accA.y += c0 * a0.y + c1 * a1.y + c2 * a2.y + c3 * a3.y;
        accA.z += c0 * a0.z + c1 * a1.z + c2 * a2.z + c3 * a3.z;
        accA.w += c0 * a0.w + c1 * a1.w + c2 * a2.w + c3 * a3.w;
        accB.x += c0 * b0.x + c1 * b1.x + c2 * b2.x + c3 * b3.x;
        accB.y += c0 * b0.y + c1 * b1.y + c2 * b2.y + c3 * b3.y;
        accB.z += c0 * b0.z + c1 * b1.z + c2 * b2.z + c3 * b3.z;
        accB.w += c0 * b0.w + c1 * b1.w + c2 * b2.w + c3 * b3.w;
    }
    for (; j < je; ++j) {
        uint2 r = sorted[j];
        float c = __uint_as_float(r.x);
        const float* p = x + (size_t)(r.y & 0xFFFFFFu) * F_DIM + h;
        float4 a = *reinterpret_cast<const float4*>(p);
        float4 bb = *reinterpret_cast<const float4*>(p + 4);
        accA.x += c * a.x;  accA.y += c * a.y;
        accA.z += c * a.z;  accA.w += c * a.w;
        accB.x += c * bb.x; accB.y += c * bb.y;
        accB.z += c * bb.z; accB.w += c * bb.w;
    }
    float4* o = reinterpret_cast<float4*>(out + (size_t)gnode * F_DIM + h);
    o[0] = accA;
    o[1] = accB;
}

// ---------------- fallback (R0): plain atomic scatter ----------------
__global__ __launch_bounds__(256) void gnn_scatter_atomic(
    const float* __restrict__ x, const int* __restrict__ src,
    const int* __restrict__ dst, const float* __restrict__ ew,
    const float* __restrict__ w_mp, float* __restrict__ out)
{
    const float w = w_mp[0];
    int gid = blockIdx.x * blockDim.x + threadIdx.x;
    int e = gid >> 3;
    int qq = (gid & 7) * 4;
    if (e >= N_EDGES) return;
    int s = src[e];
    int d = dst[e];
    float c = w * ew[e];
    const float4 xv = *reinterpret_cast<const float4*>(x + (size_t)s * F_DIM + qq);
    float* op = out + (size_t)d * F_DIM + qq;
    atomicAdd(op + 0, c * xv.x);
    atomicAdd(op + 1, c * xv.y);
    atomicAdd(op + 2, c * xv.z);
    atomicAdd(op + 3, c * xv.w);
}

extern "C" void kernel_launch(void* const* d_in, const int* in_sizes, int n_in,
                              void* d_out, int out_size, void* d_ws, size_t ws_size,
                              hipStream_t stream) {
    const float* x    = (const float*)d_in[0];
    const int*   ei   = (const int*)d_in[1];   // [2, E]: src row, then dst row
    const float* ew   = (const float*)d_in[2];
    const float* w_mp = (const float*)d_in[3];
    float* out = (float*)d_out;

    const int* src = ei;
    const int* dst = ei + N_EDGES;

    if (ws_size < WS_NEEDED) {
        hipMemsetAsync(d_out, 0, (size_t)out_size * sizeof(float), stream);
        int total = N_EDGES * 8;
        gnn_scatter_atomic<<<(total + 255) / 256, 256, 0, stream>>>(
            x, src, dst, ew, w_mp, out);
        return;
    }

    char* ws = (char*)d_ws;
    int*   gcursor = (int*)(ws + WS_CURSOR);
    uint2* records = (uint2*)(ws + WS_RECORDS);

    hipMemsetAsync(gcursor, 0, NB_C * sizeof(int), stream);
    bin_edges<<<BIN_BLOCKS, BIN_THREADS, 0, stream>>>(src, dst, ew, w_mp,
                                                      gcursor, records);
    sort_gather<<<NB_C * SUBS, SG_THREADS, 0, stream>>>(gcursor, records, x, out);
    // sort_gather writes every out element -> no d_out memset needed
}